// Round 11
// baseline (628.526 us; speedup 1.0000x reference)
//
#include <hip/hip_runtime.h>

#define N_NODES 100000
#define N_EDGES 640000
#define D 128
#define SCAN_TILE 1024
#define SCAN_BLOCKS ((N_NODES + SCAN_TILE - 1) / SCAN_TILE)  // 98

typedef __attribute__((ext_vector_type(8))) short bf16x8;   // 8 bf16 = 4 VGPRs
typedef __attribute__((ext_vector_type(4))) float f32x4;

__device__ __forceinline__ unsigned short f32_to_bf16(float f) {
  union { float f; unsigned int u; } v; v.f = f;
  unsigned int u = v.u;
  unsigned int r = (u + 0x7fffu + ((u >> 16) & 1u)) >> 16;  // RNE
  return (unsigned short)r;
}
__device__ __forceinline__ float bf16_lo(unsigned int u) { return __uint_as_float(u << 16); }
__device__ __forceinline__ float bf16_hi(unsigned int u) { return __uint_as_float(u & 0xffff0000u); }

__device__ __forceinline__ void acc8(float* a, uint4 r) {
  a[0] += bf16_lo(r.x); a[1] += bf16_hi(r.x);
  a[2] += bf16_lo(r.y); a[3] += bf16_hi(r.y);
  a[4] += bf16_lo(r.z); a[5] += bf16_hi(r.z);
  a[6] += bf16_lo(r.w); a[7] += bf16_hi(r.w);
}

// ---------------------------------------------------------------- utilities
__global__ void zero_i32(int* __restrict__ p, int n) {
  int i = blockIdx.x * blockDim.x + threadIdx.x;
  if (i < n) p[i] = 0;
}

__global__ void f32_to_bf16_vec(const float* __restrict__ in, unsigned short* __restrict__ out, int n4) {
  int i = blockIdx.x * blockDim.x + threadIdx.x;
  if (i < n4) {
    float4 v = ((const float4*)in)[i];
    ushort4 o;
    o.x = f32_to_bf16(v.x); o.y = f32_to_bf16(v.y);
    o.z = f32_to_bf16(v.z); o.w = f32_to_bf16(v.w);
    ((ushort4*)out)[i] = o;
  }
}

// 8 weight matrices [128x128] fp32 row-major [k][n] -> bf16 transposed Wt[n][k]
__global__ void transpose_w(const float* __restrict__ W0, const float* __restrict__ W1,
                            const float* __restrict__ W2, const float* __restrict__ W3,
                            const float* __restrict__ W4, const float* __restrict__ W5,
                            const float* __restrict__ W6, const float* __restrict__ W7,
                            unsigned short* __restrict__ wt) {
  int id = blockIdx.x * 256 + threadIdx.x;  // 512 blocks x 256 = 131072
  int mat = id >> 14;
  int rem = id & 16383;
  int n = rem >> 7, k = rem & 127;
  const float* Wm = mat < 4 ? (mat < 2 ? (mat == 0 ? W0 : W1) : (mat == 2 ? W2 : W3))
                            : (mat < 6 ? (mat == 4 ? W4 : W5) : (mat == 6 ? W6 : W7));
  wt[id] = f32_to_bf16(Wm[k * D + n]);
}

// ------------------------------------------------------------- CSR building (pos edges only)
__global__ void hist_kernel(const int* __restrict__ dst, int* __restrict__ deg, int E) {
  int i = blockIdx.x * blockDim.x + threadIdx.x;
  if (i < E) atomicAdd(&deg[dst[i]], 1);
}

__global__ void scan_blocksum(const int* __restrict__ deg, int* __restrict__ partial, int n) {
  __shared__ int lds[256];
  const int tid = threadIdx.x;
  const int base = blockIdx.x * SCAN_TILE + tid * 4;
  int s = 0;
#pragma unroll
  for (int j = 0; j < 4; ++j) {
    int i = base + j;
    if (i < n) s += deg[i];
  }
  lds[tid] = s;
  __syncthreads();
  for (int off = 128; off > 0; off >>= 1) {
    if (tid < off) lds[tid] += lds[tid + off];
    __syncthreads();
  }
  if (tid == 0) partial[blockIdx.x] = lds[0];
}

__global__ void scan_offsets(int* __restrict__ partial, int* __restrict__ row_start, int nb, int n) {
  __shared__ int lds[128];
  const int tid = threadIdx.x;
  int v = (tid < nb) ? partial[tid] : 0;
  lds[tid] = v;
  __syncthreads();
  for (int off = 1; off < 128; off <<= 1) {
    int t = (tid >= off) ? lds[tid - off] : 0;
    __syncthreads();
    lds[tid] += t;
    __syncthreads();
  }
  if (tid < nb) partial[tid] = (tid == 0) ? 0 : lds[tid - 1];
  if (tid == 0) row_start[n] = lds[nb - 1];
}

__global__ void scan_final(const int* __restrict__ deg, const int* __restrict__ partial,
                           int* __restrict__ row_start, int n) {
  __shared__ int lds[256];
  const int tid = threadIdx.x;
  const int base = blockIdx.x * SCAN_TILE + tid * 4;
  int d[4];
  int s = 0;
#pragma unroll
  for (int j = 0; j < 4; ++j) {
    int i = base + j;
    d[j] = (i < n) ? deg[i] : 0;
    s += d[j];
  }
  lds[tid] = s;
  __syncthreads();
  for (int off = 1; off < 256; off <<= 1) {
    int t = (tid >= off) ? lds[tid - off] : 0;
    __syncthreads();
    lds[tid] += t;
    __syncthreads();
  }
  int pre = partial[blockIdx.x] + lds[tid] - s;
#pragma unroll
  for (int j = 0; j < 4; ++j) {
    int i = base + j;
    if (i < n) {
      row_start[i] = pre;
      pre += d[j];
    }
  }
}

__global__ void fill_kernel(const int* __restrict__ src, const int* __restrict__ dst,
                            const int* __restrict__ row_start, int* __restrict__ cursor,
                            int* __restrict__ esrc, int E) {
  int i = blockIdx.x * blockDim.x + threadIdx.x;
  if (i < E) {
    int d = dst[i];
    int pos = atomicAdd(&cursor[d], 1);
    esrc[row_start[d] + pos] = src[i];
  }
}

// ----------------------------------------------------- fused SAGE layer
// Block = 64 nodes. Phase 1: gather mean(h[neigh]) -> LDS tile (never global).
// Phase 2: out = h@Ws + mean@Wn + b via MFMA.
// Weights are NOT LDS-staged: B-fragments stream from L2 (identical addresses
// across all blocks -> L2-resident), s-outer/t-inner = 8 independent chains.
// LDS = mean tile only (17.4 KB) -> ~7-8 blocks/CU so the gather phase has
// ~28 waves/CU of latency hiding (round-10's 52 KB LDS gave only 3 blocks/CU).
// PRED variant (layer 3): keep h3 in LDS, two more streamed-weight passes
// produce A = h3@WtA + biasA and B = h3@WtB directly (h3 never hits HBM).
template <bool PRED>
__global__ __launch_bounds__(256) void layer_fused(
    const unsigned short* __restrict__ hin,
    const int* __restrict__ row_start, const int* __restrict__ esrc,
    const unsigned short* __restrict__ Wts, const unsigned short* __restrict__ Wtn,
    const float* __restrict__ bias,
    const unsigned short* __restrict__ WtA, const unsigned short* __restrict__ WtB,
    const float* __restrict__ biasA,
    unsigned short* __restrict__ out0, unsigned short* __restrict__ out1, int M) {
  __shared__ unsigned short mt[64][136];   // 17.4 KB mean tile (reused as h3 tile)
  const int tid = threadIdx.x;
  const int lane = tid & 63;
  const int wave = tid >> 6;
  const int m0 = blockIdx.x * 64;
  const int row = lane & 15;
  const int q = lane >> 4;
  const int mw = m0 + wave * 16;
  const int mload = min(mw + row, M - 1);

  // ---- A fragments of hin ----
  bf16x8 ah[4];
#pragma unroll
  for (int s = 0; s < 4; ++s)
    ah[s] = *reinterpret_cast<const bf16x8*>(hin + (size_t)mload * D + s * 32 + q * 8);

  // ---- phase 1: gather means into mt. group g (16 lanes) handles 4 nodes ----
  {
    const int g = tid >> 4;   // 0..15
    const int fl = tid & 15;  // feature lane, 16 B each
    for (int j = 0; j < 4; ++j) {
      const int node = m0 + g * 4 + j;
      float ac[8] = {0.f, 0.f, 0.f, 0.f, 0.f, 0.f, 0.f, 0.f};
      if (node < M) {
        const int s0 = row_start[node], s1 = row_start[node + 1];
        int e = s0;
        for (; e + 4 <= s1; e += 4) {
          int i0 = esrc[e], i1 = esrc[e + 1], i2 = esrc[e + 2], i3 = esrc[e + 3];
          uint4 r0 = *(const uint4*)(hin + (size_t)i0 * D + fl * 8);
          uint4 r1 = *(const uint4*)(hin + (size_t)i1 * D + fl * 8);
          uint4 r2 = *(const uint4*)(hin + (size_t)i2 * D + fl * 8);
          uint4 r3 = *(const uint4*)(hin + (size_t)i3 * D + fl * 8);
          acc8(ac, r0); acc8(ac, r1); acc8(ac, r2); acc8(ac, r3);
        }
        for (; e < s1; ++e) {
          uint4 r0 = *(const uint4*)(hin + (size_t)esrc[e] * D + fl * 8);
          acc8(ac, r0);
        }
        const float inv = 1.0f / (float)max(s1 - s0, 1);
#pragma unroll
        for (int k = 0; k < 8; ++k) ac[k] *= inv;
      }
      uint4 o;
      o.x = (unsigned)f32_to_bf16(ac[0]) | ((unsigned)f32_to_bf16(ac[1]) << 16);
      o.y = (unsigned)f32_to_bf16(ac[2]) | ((unsigned)f32_to_bf16(ac[3]) << 16);
      o.z = (unsigned)f32_to_bf16(ac[4]) | ((unsigned)f32_to_bf16(ac[5]) << 16);
      o.w = (unsigned)f32_to_bf16(ac[6]) | ((unsigned)f32_to_bf16(ac[7]) << 16);
      *reinterpret_cast<uint4*>(&mt[g * 4 + j][fl * 8]) = o;
    }
  }
  __syncthreads();  // mt = mean ready

  // ---- mean A-fragments from LDS ----
  const int lrow = wave * 16 + row;  // local row 0..63
  bf16x8 am[4];
#pragma unroll
  for (int s = 0; s < 4; ++s)
    am[s] = *reinterpret_cast<const bf16x8*>(&mt[lrow][s * 32 + q * 8]);

  f32x4 acc[8];
#pragma unroll
  for (int t = 0; t < 8; ++t) acc[t] = (f32x4){0.f, 0.f, 0.f, 0.f};

  // ---- K chunk 0: hin @ Ws (B streamed from L2, 8 independent chains) ----
#pragma unroll
  for (int s = 0; s < 4; ++s)
#pragma unroll
    for (int t = 0; t < 8; ++t) {
      bf16x8 b = *reinterpret_cast<const bf16x8*>(Wts + (size_t)(t * 16 + row) * D + s * 32 + q * 8);
      acc[t] = __builtin_amdgcn_mfma_f32_16x16x32_bf16(ah[s], b, acc[t], 0, 0, 0);
    }
  // ---- K chunk 1: mean @ Wn ----
#pragma unroll
  for (int s = 0; s < 4; ++s)
#pragma unroll
    for (int t = 0; t < 8; ++t) {
      bf16x8 b = *reinterpret_cast<const bf16x8*>(Wtn + (size_t)(t * 16 + row) * D + s * 32 + q * 8);
      acc[t] = __builtin_amdgcn_mfma_f32_16x16x32_bf16(am[s], b, acc[t], 0, 0, 0);
    }

  if (!PRED) {
    // ---- epilogue: out0 = acc + bias (bf16) ----
#pragma unroll
    for (int t = 0; t < 8; ++t) {
      const int col = t * 16 + row;
      const float bv = bias[col];
#pragma unroll
      for (int r = 0; r < 4; ++r) {
        int m = mw + q * 4 + r;
        if (m < M) out0[(size_t)m * D + col] = f32_to_bf16(acc[t][r] + bv);
      }
    }
    return;
  }

  // ================= PRED tail (layer 3) =================
  __syncthreads();  // all waves done reading mt (mean fragments)
  // ---- h3 (bf16, bias applied) into mt ----
#pragma unroll
  for (int t = 0; t < 8; ++t) {
    const int col = t * 16 + row;
    const float bv = bias[col];
#pragma unroll
    for (int r = 0; r < 4; ++r)
      mt[wave * 16 + q * 4 + r][col] = f32_to_bf16(acc[t][r] + bv);
  }
  __syncthreads();
  // ---- h3 A-fragments ----
  bf16x8 ap[4];
#pragma unroll
  for (int s = 0; s < 4; ++s)
    ap[s] = *reinterpret_cast<const bf16x8*>(&mt[lrow][s * 32 + q * 8]);

  // ---- A = h3 @ WtA + biasA ----
#pragma unroll
  for (int t = 0; t < 8; ++t) acc[t] = (f32x4){0.f, 0.f, 0.f, 0.f};
#pragma unroll
  for (int s = 0; s < 4; ++s)
#pragma unroll
    for (int t = 0; t < 8; ++t) {
      bf16x8 b = *reinterpret_cast<const bf16x8*>(WtA + (size_t)(t * 16 + row) * D + s * 32 + q * 8);
      acc[t] = __builtin_amdgcn_mfma_f32_16x16x32_bf16(ap[s], b, acc[t], 0, 0, 0);
    }
#pragma unroll
  for (int t = 0; t < 8; ++t) {
    const int col = t * 16 + row;
    const float bv = biasA[col];
#pragma unroll
    for (int r = 0; r < 4; ++r) {
      int m = mw + q * 4 + r;
      if (m < M) out0[(size_t)m * D + col] = f32_to_bf16(acc[t][r] + bv);
    }
  }
  // ---- B = h3 @ WtB ----
#pragma unroll
  for (int t = 0; t < 8; ++t) acc[t] = (f32x4){0.f, 0.f, 0.f, 0.f};
#pragma unroll
  for (int s = 0; s < 4; ++s)
#pragma unroll
    for (int t = 0; t < 8; ++t) {
      bf16x8 b = *reinterpret_cast<const bf16x8*>(WtB + (size_t)(t * 16 + row) * D + s * 32 + q * 8);
      acc[t] = __builtin_amdgcn_mfma_f32_16x16x32_bf16(ap[s], b, acc[t], 0, 0, 0);
    }
#pragma unroll
  for (int t = 0; t < 8; ++t) {
    const int col = t * 16 + row;
#pragma unroll
    for (int r = 0; r < 4; ++r) {
      int m = mw + q * 4 + r;
      if (m < M) out1[(size_t)m * D + col] = f32_to_bf16(acc[t][r]);
    }
  }
}

// ----------------------------------------------------- fused pos+neg edge MLP score
// group g scores pos edge g AND neg edge g: 4 independent row gathers in flight.
// score = relu(A[s]+B[d]).Wp2 + bp2  (bp1 folded into A)
__global__ void edge_score_fused(const unsigned short* __restrict__ A, const unsigned short* __restrict__ B,
                                 const int* __restrict__ ps, const int* __restrict__ pd,
                                 const int* __restrict__ ns, const int* __restrict__ nd,
                                 const float* __restrict__ Wp2, const float* __restrict__ bp2,
                                 float* __restrict__ out, int E) {
  const int t = blockIdx.x * blockDim.x + threadIdx.x;
  const int e = t >> 4;                 // 16 lanes per edge pair
  const int fl = threadIdx.x & 15;
  if (e >= E) return;
  const int si = ps[e], di = pd[e];
  const int nsi = ns[e], ndi = nd[e];
  uint4 ra = *(const uint4*)(A + (size_t)si * D + fl * 8);
  uint4 rb = *(const uint4*)(B + (size_t)di * D + fl * 8);
  uint4 rna = *(const uint4*)(A + (size_t)nsi * D + fl * 8);
  uint4 rnb = *(const uint4*)(B + (size_t)ndi * D + fl * 8);
  float4 w0 = *(const float4*)(Wp2 + fl * 8);
  float4 w1 = *(const float4*)(Wp2 + fl * 8 + 4);

  float pp =
      fmaxf(bf16_lo(ra.x) + bf16_lo(rb.x), 0.f) * w0.x +
      fmaxf(bf16_hi(ra.x) + bf16_hi(rb.x), 0.f) * w0.y +
      fmaxf(bf16_lo(ra.y) + bf16_lo(rb.y), 0.f) * w0.z +
      fmaxf(bf16_hi(ra.y) + bf16_hi(rb.y), 0.f) * w0.w +
      fmaxf(bf16_lo(ra.z) + bf16_lo(rb.z), 0.f) * w1.x +
      fmaxf(bf16_hi(ra.z) + bf16_hi(rb.z), 0.f) * w1.y +
      fmaxf(bf16_lo(ra.w) + bf16_lo(rb.w), 0.f) * w1.z +
      fmaxf(bf16_hi(ra.w) + bf16_hi(rb.w), 0.f) * w1.w;
  float pn =
      fmaxf(bf16_lo(rna.x) + bf16_lo(rnb.x), 0.f) * w0.x +
      fmaxf(bf16_hi(rna.x) + bf16_hi(rnb.x), 0.f) * w0.y +
      fmaxf(bf16_lo(rna.y) + bf16_lo(rnb.y), 0.f) * w0.z +
      fmaxf(bf16_hi(rna.y) + bf16_hi(rnb.y), 0.f) * w0.w +
      fmaxf(bf16_lo(rna.z) + bf16_lo(rnb.z), 0.f) * w1.x +
      fmaxf(bf16_hi(rna.z) + bf16_hi(rnb.z), 0.f) * w1.y +
      fmaxf(bf16_lo(rna.w) + bf16_lo(rnb.w), 0.f) * w1.z +
      fmaxf(bf16_hi(rna.w) + bf16_hi(rnb.w), 0.f) * w1.w;

  pp += __shfl_xor(pp, 1);  pn += __shfl_xor(pn, 1);
  pp += __shfl_xor(pp, 2);  pn += __shfl_xor(pn, 2);
  pp += __shfl_xor(pp, 4);  pn += __shfl_xor(pn, 4);
  pp += __shfl_xor(pp, 8);  pn += __shfl_xor(pn, 8);
  if (fl == 0) {
    float b = bp2[0];
    out[e] = pp + b;
    out[E + e] = pn + b;
  }
}

// ---------------------------------------------------------------- launcher
extern "C" void kernel_launch(void* const* d_in, const int* in_sizes, int n_in,
                              void* d_out, int out_size, void* d_ws, size_t ws_size,
                              hipStream_t stream) {
  const float* x = (const float*)d_in[0];
  const int* src = (const int*)d_in[1];
  const int* dst = (const int*)d_in[2];
  const int* nsrc = (const int*)d_in[3];
  const int* ndst = (const int*)d_in[4];
  const float* Ws1 = (const float*)d_in[5];
  const float* Wn1 = (const float*)d_in[6];
  const float* b1 = (const float*)d_in[7];
  const float* Ws2 = (const float*)d_in[8];
  const float* Wn2 = (const float*)d_in[9];
  const float* b2 = (const float*)d_in[10];
  const float* Ws3 = (const float*)d_in[11];
  const float* Wn3 = (const float*)d_in[12];
  const float* b3 = (const float*)d_in[13];
  const float* Wp1 = (const float*)d_in[14];
  const float* bp1 = (const float*)d_in[15];
  const float* Wp2 = (const float*)d_in[16];
  const float* bp2 = (const float*)d_in[17];
  float* out = (float*)d_out;

  char* ws = (char*)d_ws;
  size_t off = 0;
  auto alloc = [&](size_t bytes) -> void* {
    void* p = ws + off;
    off += (bytes + 255) & ~(size_t)255;
    return p;
  };
  const size_t NODE_F32 = sizeof(float) * (size_t)N_NODES * D;  // 51.2 MB
  char* region0 = (char*)alloc(NODE_F32);   // bf16 xb | (spare) -> later bf16 Ab | Bb
  char* region1 = (char*)alloc(NODE_F32);   // bf16 hA | hB
  int* row_start = (int*)alloc(sizeof(int) * (N_NODES + 1));
  int* deg = (int*)alloc(sizeof(int) * N_NODES * 2);  // deg + cursor
  int* cursor = deg + N_NODES;
  int* esrc = (int*)alloc(sizeof(int) * N_EDGES);
  int* partial = (int*)alloc(sizeof(int) * 128);
  unsigned short* wt = (unsigned short*)alloc(sizeof(unsigned short) * 8 * D * D);
  (void)ws_size;

  unsigned short* xb = (unsigned short*)region0;
  unsigned short* hA = (unsigned short*)region1;
  unsigned short* hB = hA + (size_t)N_NODES * D;
  unsigned short* Ab = xb;                              // xb dead after layer-1 kernel
  unsigned short* Bb = xb + (size_t)N_NODES * D;        // second half of region0 (unused otherwise)

  // ---- conversions
  f32_to_bf16_vec<<<(N_NODES * D / 4 + 255) / 256, 256, 0, stream>>>(x, xb, N_NODES * D / 4);
  transpose_w<<<512, 256, 0, stream>>>(Ws1, Wn1, Ws2, Wn2, Ws3, Wn3, Wp1, Wp1 + D * D, wt);

  // ---- CSR build (pos edges; reused by all 3 layers)
  zero_i32<<<(2 * N_NODES + 255) / 256, 256, 0, stream>>>(deg, 2 * N_NODES);
  hist_kernel<<<(N_EDGES + 255) / 256, 256, 0, stream>>>(dst, deg, N_EDGES);
  scan_blocksum<<<SCAN_BLOCKS, 256, 0, stream>>>(deg, partial, N_NODES);
  scan_offsets<<<1, 128, 0, stream>>>(partial, row_start, SCAN_BLOCKS, N_NODES);
  scan_final<<<SCAN_BLOCKS, 256, 0, stream>>>(deg, partial, row_start, N_NODES);
  fill_kernel<<<(N_EDGES + 255) / 256, 256, 0, stream>>>(src, dst, row_start, cursor, esrc, N_EDGES);

  const int layerBlocks = (N_NODES + 63) / 64;
  const int edgeBlocks = (N_EDGES * 16) / 256;  // 16 lanes/edge-pair

  // ---- layer 1: h1 = x@Ws1 + mean(x)@Wn1 + b1  (mean via LDS)
  layer_fused<false><<<layerBlocks, 256, 0, stream>>>(
      xb, row_start, esrc, wt, wt + 16384, b1, nullptr, nullptr, nullptr, hA, nullptr, N_NODES);
  // ---- layer 2
  layer_fused<false><<<layerBlocks, 256, 0, stream>>>(
      hA, row_start, esrc, wt + 2 * 16384, wt + 3 * 16384, b2, nullptr, nullptr, nullptr, hB, nullptr, N_NODES);
  // ---- layer 3 + predictor: Ab = h3@Wp1_top + bp1, Bb = h3@Wp1_bot (h3 never leaves LDS)
  layer_fused<true><<<layerBlocks, 256, 0, stream>>>(
      hB, row_start, esrc, wt + 4 * 16384, wt + 5 * 16384, b3, wt + 6 * 16384, wt + 7 * 16384, bp1,
      Ab, Bb, N_NODES);
  // ---- edge scores (pos + neg fused)
  edge_score_fused<<<edgeBlocks, 256, 0, stream>>>(Ab, Bb, src, dst, nsrc, ndst, Wp2, bp2, out, N_EDGES);
}

// Round 12
// 500.435 us; speedup vs baseline: 1.2560x; 1.2560x over previous
//
#include <hip/hip_runtime.h>

#define N_NODES 100000
#define N_EDGES 640000
#define D 128
#define SCAN_TILE 1024
#define SCAN_BLOCKS ((N_NODES + SCAN_TILE - 1) / SCAN_TILE)  // 98

typedef __attribute__((ext_vector_type(8))) short bf16x8;   // 8 bf16 = 4 VGPRs
typedef __attribute__((ext_vector_type(4))) float f32x4;

__device__ __forceinline__ unsigned short f32_to_bf16(float f) {
  union { float f; unsigned int u; } v; v.f = f;
  unsigned int u = v.u;
  unsigned int r = (u + 0x7fffu + ((u >> 16) & 1u)) >> 16;  // RNE
  return (unsigned short)r;
}
__device__ __forceinline__ float bf16_lo(unsigned int u) { return __uint_as_float(u << 16); }
__device__ __forceinline__ float bf16_hi(unsigned int u) { return __uint_as_float(u & 0xffff0000u); }

__device__ __forceinline__ void acc8(float* a, uint4 r) {
  a[0] += bf16_lo(r.x); a[1] += bf16_hi(r.x);
  a[2] += bf16_lo(r.y); a[3] += bf16_hi(r.y);
  a[4] += bf16_lo(r.z); a[5] += bf16_hi(r.z);
  a[6] += bf16_lo(r.w); a[7] += bf16_hi(r.w);
}

// ---------------------------------------------------------------- utilities
__global__ void zero_i32(int* __restrict__ p, int n) {
  int i = blockIdx.x * blockDim.x + threadIdx.x;
  if (i < n) p[i] = 0;
}

__global__ void f32_to_bf16_vec(const float* __restrict__ in, unsigned short* __restrict__ out, int n4) {
  int i = blockIdx.x * blockDim.x + threadIdx.x;
  if (i < n4) {
    float4 v = ((const float4*)in)[i];
    ushort4 o;
    o.x = f32_to_bf16(v.x); o.y = f32_to_bf16(v.y);
    o.z = f32_to_bf16(v.z); o.w = f32_to_bf16(v.w);
    ((ushort4*)out)[i] = o;
  }
}

// 8 weight matrices [128x128] fp32 row-major [k][n] -> bf16 transposed Wt[n][k]
__global__ void transpose_w(const float* __restrict__ W0, const float* __restrict__ W1,
                            const float* __restrict__ W2, const float* __restrict__ W3,
                            const float* __restrict__ W4, const float* __restrict__ W5,
                            const float* __restrict__ W6, const float* __restrict__ W7,
                            unsigned short* __restrict__ wt) {
  int id = blockIdx.x * 256 + threadIdx.x;  // 512 blocks x 256 = 131072
  int mat = id >> 14;
  int rem = id & 16383;
  int n = rem >> 7, k = rem & 127;
  const float* Wm = mat < 4 ? (mat < 2 ? (mat == 0 ? W0 : W1) : (mat == 2 ? W2 : W3))
                            : (mat < 6 ? (mat == 4 ? W4 : W5) : (mat == 6 ? W6 : W7));
  wt[id] = f32_to_bf16(Wm[k * D + n]);
}

// ------------------------------------------------------------- CSR building (pos edges only)
__global__ void hist_kernel(const int* __restrict__ dst, int* __restrict__ deg, int E) {
  int i = blockIdx.x * blockDim.x + threadIdx.x;
  if (i < E) atomicAdd(&deg[dst[i]], 1);
}

__global__ void scan_blocksum(const int* __restrict__ deg, int* __restrict__ partial, int n) {
  __shared__ int lds[256];
  const int tid = threadIdx.x;
  const int base = blockIdx.x * SCAN_TILE + tid * 4;
  int s = 0;
#pragma unroll
  for (int j = 0; j < 4; ++j) {
    int i = base + j;
    if (i < n) s += deg[i];
  }
  lds[tid] = s;
  __syncthreads();
  for (int off = 128; off > 0; off >>= 1) {
    if (tid < off) lds[tid] += lds[tid + off];
    __syncthreads();
  }
  if (tid == 0) partial[blockIdx.x] = lds[0];
}

__global__ void scan_offsets(int* __restrict__ partial, int* __restrict__ row_start, int nb, int n) {
  __shared__ int lds[128];
  const int tid = threadIdx.x;
  int v = (tid < nb) ? partial[tid] : 0;
  lds[tid] = v;
  __syncthreads();
  for (int off = 1; off < 128; off <<= 1) {
    int t = (tid >= off) ? lds[tid - off] : 0;
    __syncthreads();
    lds[tid] += t;
    __syncthreads();
  }
  if (tid < nb) partial[tid] = (tid == 0) ? 0 : lds[tid - 1];
  if (tid == 0) row_start[n] = lds[nb - 1];
}

__global__ void scan_final(const int* __restrict__ deg, const int* __restrict__ partial,
                           int* __restrict__ row_start, int n) {
  __shared__ int lds[256];
  const int tid = threadIdx.x;
  const int base = blockIdx.x * SCAN_TILE + tid * 4;
  int d[4];
  int s = 0;
#pragma unroll
  for (int j = 0; j < 4; ++j) {
    int i = base + j;
    d[j] = (i < n) ? deg[i] : 0;
    s += d[j];
  }
  lds[tid] = s;
  __syncthreads();
  for (int off = 1; off < 256; off <<= 1) {
    int t = (tid >= off) ? lds[tid - off] : 0;
    __syncthreads();
    lds[tid] += t;
    __syncthreads();
  }
  int pre = partial[blockIdx.x] + lds[tid] - s;
#pragma unroll
  for (int j = 0; j < 4; ++j) {
    int i = base + j;
    if (i < n) {
      row_start[i] = pre;
      pre += d[j];
    }
  }
}

__global__ void fill_kernel(const int* __restrict__ src, const int* __restrict__ dst,
                            const int* __restrict__ row_start, int* __restrict__ cursor,
                            int* __restrict__ esrc, int E) {
  int i = blockIdx.x * blockDim.x + threadIdx.x;
  if (i < E) {
    int d = dst[i];
    int pos = atomicAdd(&cursor[d], 1);
    esrc[row_start[d] + pos] = src[i];
  }
}

// ----------------------------------------------------- fused SAGE layer
// Block = 64 nodes. Phase 1: gather mean(h[neigh]) -> LDS tile (never global).
// Phase 2: out = h@Ws + mean@Wn + b via MFMA.
// Weights staged in HALF-N PANELS (wl[64][136], 17.4 KB) so total LDS = 34.8 KB
// -> 4 blocks/CU (round-10's full 128-row tile gave 52 KB -> 3 blocks/CU; the
// extra block is +33% gather latency-hiding). Round-11 showed streaming B from
// L2 inside the MFMA loop is 2x WORSE (latency-serialized) - LDS is mandatory.
// PRED variant (layer 3): keep h3 in LDS, two more weight matrices produce
// A = h3@WtA + biasA and B = h3@WtB directly (h3 never hits HBM).
template <bool PRED>
__global__ __launch_bounds__(256) void layer_fused(
    const unsigned short* __restrict__ hin,
    const int* __restrict__ row_start, const int* __restrict__ esrc,
    const unsigned short* __restrict__ Wts, const unsigned short* __restrict__ Wtn,
    const float* __restrict__ bias,
    const unsigned short* __restrict__ WtA, const unsigned short* __restrict__ WtB,
    const float* __restrict__ biasA,
    unsigned short* __restrict__ out0, unsigned short* __restrict__ out1, int M) {
  __shared__ unsigned short wl[64][136];   // 17.4 KB half-n weight panel
  __shared__ unsigned short mt[64][136];   // 17.4 KB mean tile (reused as h3 tile)
  const int tid = threadIdx.x;
  const int lane = tid & 63;
  const int wave = tid >> 6;
  const int m0 = blockIdx.x * 64;
  const int row = lane & 15;
  const int q = lane >> 4;
  const int mw = m0 + wave * 16;
  const int mload = min(mw + row, M - 1);

  // stage rows [half*64, half*64+64) of a transposed weight matrix into wl
  auto stage64 = [&](const unsigned short* W, int half) {
#pragma unroll
    for (int i = 0; i < 4; ++i) {
      int seg = i * 256 + tid;
      int r = seg >> 4, o = (seg & 15) * 8;
      *reinterpret_cast<bf16x8*>(&wl[r][o]) =
          *reinterpret_cast<const bf16x8*>(W + (size_t)(half * 64 + r) * D + o);
    }
  };
  // 16 MFMAs of one half-panel into acc[base..base+3]
  auto mfma_half = [&](bf16x8* a, f32x4* accp) {
#pragma unroll
    for (int s = 0; s < 4; ++s)
#pragma unroll
      for (int t = 0; t < 4; ++t) {
        bf16x8 b = *reinterpret_cast<const bf16x8*>(&wl[t * 16 + row][s * 32 + q * 8]);
        accp[t] = __builtin_amdgcn_mfma_f32_16x16x32_bf16(a[s], b, accp[t], 0, 0, 0);
      }
  };

  // ---- A fragments of hin ----
  bf16x8 ah[4];
#pragma unroll
  for (int s = 0; s < 4; ++s)
    ah[s] = *reinterpret_cast<const bf16x8*>(hin + (size_t)mload * D + s * 32 + q * 8);

  // ---- stage Ws half 0 (overlaps with gather; gather doesn't touch wl) ----
  stage64(Wts, 0);

  // ---- phase 1: gather means into mt. group g (16 lanes) handles 4 nodes ----
  {
    const int g = tid >> 4;   // 0..15
    const int fl = tid & 15;  // feature lane, 16 B each
    for (int j = 0; j < 4; ++j) {
      const int node = m0 + g * 4 + j;
      float ac[8] = {0.f, 0.f, 0.f, 0.f, 0.f, 0.f, 0.f, 0.f};
      if (node < M) {
        const int s0 = row_start[node], s1 = row_start[node + 1];
        int e = s0;
        for (; e + 4 <= s1; e += 4) {
          int i0 = esrc[e], i1 = esrc[e + 1], i2 = esrc[e + 2], i3 = esrc[e + 3];
          uint4 r0 = *(const uint4*)(hin + (size_t)i0 * D + fl * 8);
          uint4 r1 = *(const uint4*)(hin + (size_t)i1 * D + fl * 8);
          uint4 r2 = *(const uint4*)(hin + (size_t)i2 * D + fl * 8);
          uint4 r3 = *(const uint4*)(hin + (size_t)i3 * D + fl * 8);
          acc8(ac, r0); acc8(ac, r1); acc8(ac, r2); acc8(ac, r3);
        }
        for (; e < s1; ++e) {
          uint4 r0 = *(const uint4*)(hin + (size_t)esrc[e] * D + fl * 8);
          acc8(ac, r0);
        }
        const float inv = 1.0f / (float)max(s1 - s0, 1);
#pragma unroll
        for (int k = 0; k < 8; ++k) ac[k] *= inv;
      }
      uint4 o;
      o.x = (unsigned)f32_to_bf16(ac[0]) | ((unsigned)f32_to_bf16(ac[1]) << 16);
      o.y = (unsigned)f32_to_bf16(ac[2]) | ((unsigned)f32_to_bf16(ac[3]) << 16);
      o.z = (unsigned)f32_to_bf16(ac[4]) | ((unsigned)f32_to_bf16(ac[5]) << 16);
      o.w = (unsigned)f32_to_bf16(ac[6]) | ((unsigned)f32_to_bf16(ac[7]) << 16);
      *reinterpret_cast<uint4*>(&mt[g * 4 + j][fl * 8]) = o;
    }
  }
  __syncthreads();  // wl = Ws[0:64) and mt = mean ready

  // ---- mean A-fragments from LDS ----
  const int lrow = wave * 16 + row;  // local row 0..63
  bf16x8 am[4];
#pragma unroll
  for (int s = 0; s < 4; ++s)
    am[s] = *reinterpret_cast<const bf16x8*>(&mt[lrow][s * 32 + q * 8]);

  f32x4 acc[8];
#pragma unroll
  for (int t = 0; t < 8; ++t) acc[t] = (f32x4){0.f, 0.f, 0.f, 0.f};

  mfma_half(ah, acc);                 // hin @ Ws, n 0..63
  __syncthreads(); stage64(Wts, 1); __syncthreads();
  mfma_half(ah, acc + 4);             // hin @ Ws, n 64..127
  __syncthreads(); stage64(Wtn, 0); __syncthreads();
  mfma_half(am, acc);                 // mean @ Wn, n 0..63
  __syncthreads(); stage64(Wtn, 1); __syncthreads();
  mfma_half(am, acc + 4);             // mean @ Wn, n 64..127

  if (!PRED) {
#pragma unroll
    for (int t = 0; t < 8; ++t) {
      const int col = t * 16 + row;
      const float bv = bias[col];
#pragma unroll
      for (int r = 0; r < 4; ++r) {
        int m = mw + q * 4 + r;
        if (m < M) out0[(size_t)m * D + col] = f32_to_bf16(acc[t][r] + bv);
      }
    }
    return;
  }

  // ================= PRED tail (layer 3) =================
  __syncthreads();  // all waves done with wl(WtN half1) and mt(mean)
  // ---- h3 (bf16, bias applied) into mt; stage WtA half 0 ----
#pragma unroll
  for (int t = 0; t < 8; ++t) {
    const int col = t * 16 + row;
    const float bv = bias[col];
#pragma unroll
    for (int r = 0; r < 4; ++r)
      mt[wave * 16 + q * 4 + r][col] = f32_to_bf16(acc[t][r] + bv);
  }
  stage64(WtA, 0);
  __syncthreads();
  // ---- h3 A-fragments ----
  bf16x8 ap[4];
#pragma unroll
  for (int s = 0; s < 4; ++s)
    ap[s] = *reinterpret_cast<const bf16x8*>(&mt[lrow][s * 32 + q * 8]);

#pragma unroll
  for (int t = 0; t < 8; ++t) acc[t] = (f32x4){0.f, 0.f, 0.f, 0.f};
  mfma_half(ap, acc);                 // h3 @ WtA, n 0..63
  __syncthreads(); stage64(WtA, 1); __syncthreads();
  mfma_half(ap, acc + 4);             // h3 @ WtA, n 64..127
#pragma unroll
  for (int t = 0; t < 8; ++t) {
    const int col = t * 16 + row;
    const float bv = biasA[col];
#pragma unroll
    for (int r = 0; r < 4; ++r) {
      int m = mw + q * 4 + r;
      if (m < M) out0[(size_t)m * D + col] = f32_to_bf16(acc[t][r] + bv);
    }
  }
  __syncthreads(); stage64(WtB, 0); __syncthreads();
#pragma unroll
  for (int t = 0; t < 8; ++t) acc[t] = (f32x4){0.f, 0.f, 0.f, 0.f};
  mfma_half(ap, acc);                 // h3 @ WtB, n 0..63
  __syncthreads(); stage64(WtB, 1); __syncthreads();
  mfma_half(ap, acc + 4);             // h3 @ WtB, n 64..127
#pragma unroll
  for (int t = 0; t < 8; ++t) {
    const int col = t * 16 + row;
#pragma unroll
    for (int r = 0; r < 4; ++r) {
      int m = mw + q * 4 + r;
      if (m < M) out1[(size_t)m * D + col] = f32_to_bf16(acc[t][r]);
    }
  }
}

// ----------------------------------------------------- fused pos+neg edge MLP score
// group g scores pos edge g AND neg edge g: 4 independent row gathers in flight.
// score = relu(A[s]+B[d]).Wp2 + bp2  (bp1 folded into A)
__global__ void edge_score_fused(const unsigned short* __restrict__ A, const unsigned short* __restrict__ B,
                                 const int* __restrict__ ps, const int* __restrict__ pd,
                                 const int* __restrict__ ns, const int* __restrict__ nd,
                                 const float* __restrict__ Wp2, const float* __restrict__ bp2,
                                 float* __restrict__ out, int E) {
  const int t = blockIdx.x * blockDim.x + threadIdx.x;
  const int e = t >> 4;                 // 16 lanes per edge pair
  const int fl = threadIdx.x & 15;
  if (e >= E) return;
  const int si = ps[e], di = pd[e];
  const int nsi = ns[e], ndi = nd[e];
  uint4 ra = *(const uint4*)(A + (size_t)si * D + fl * 8);
  uint4 rb = *(const uint4*)(B + (size_t)di * D + fl * 8);
  uint4 rna = *(const uint4*)(A + (size_t)nsi * D + fl * 8);
  uint4 rnb = *(const uint4*)(B + (size_t)ndi * D + fl * 8);
  float4 w0 = *(const float4*)(Wp2 + fl * 8);
  float4 w1 = *(const float4*)(Wp2 + fl * 8 + 4);

  float pp =
      fmaxf(bf16_lo(ra.x) + bf16_lo(rb.x), 0.f) * w0.x +
      fmaxf(bf16_hi(ra.x) + bf16_hi(rb.x), 0.f) * w0.y +
      fmaxf(bf16_lo(ra.y) + bf16_lo(rb.y), 0.f) * w0.z +
      fmaxf(bf16_hi(ra.y) + bf16_hi(rb.y), 0.f) * w0.w +
      fmaxf(bf16_lo(ra.z) + bf16_lo(rb.z), 0.f) * w1.x +
      fmaxf(bf16_hi(ra.z) + bf16_hi(rb.z), 0.f) * w1.y +
      fmaxf(bf16_lo(ra.w) + bf16_lo(rb.w), 0.f) * w1.z +
      fmaxf(bf16_hi(ra.w) + bf16_hi(rb.w), 0.f) * w1.w;
  float pn =
      fmaxf(bf16_lo(rna.x) + bf16_lo(rnb.x), 0.f) * w0.x +
      fmaxf(bf16_hi(rna.x) + bf16_hi(rnb.x), 0.f) * w0.y +
      fmaxf(bf16_lo(rna.y) + bf16_lo(rnb.y), 0.f) * w0.z +
      fmaxf(bf16_hi(rna.y) + bf16_hi(rnb.y), 0.f) * w0.w +
      fmaxf(bf16_lo(rna.z) + bf16_lo(rnb.z), 0.f) * w1.x +
      fmaxf(bf16_hi(rna.z) + bf16_hi(rnb.z), 0.f) * w1.y +
      fmaxf(bf16_lo(rna.w) + bf16_lo(rnb.w), 0.f) * w1.z +
      fmaxf(bf16_hi(rna.w) + bf16_hi(rnb.w), 0.f) * w1.w;

  pp += __shfl_xor(pp, 1);  pn += __shfl_xor(pn, 1);
  pp += __shfl_xor(pp, 2);  pn += __shfl_xor(pn, 2);
  pp += __shfl_xor(pp, 4);  pn += __shfl_xor(pn, 4);
  pp += __shfl_xor(pp, 8);  pn += __shfl_xor(pn, 8);
  if (fl == 0) {
    float b = bp2[0];
    out[e] = pp + b;
    out[E + e] = pn + b;
  }
}

// ---------------------------------------------------------------- launcher
extern "C" void kernel_launch(void* const* d_in, const int* in_sizes, int n_in,
                              void* d_out, int out_size, void* d_ws, size_t ws_size,
                              hipStream_t stream) {
  const float* x = (const float*)d_in[0];
  const int* src = (const int*)d_in[1];
  const int* dst = (const int*)d_in[2];
  const int* nsrc = (const int*)d_in[3];
  const int* ndst = (const int*)d_in[4];
  const float* Ws1 = (const float*)d_in[5];
  const float* Wn1 = (const float*)d_in[6];
  const float* b1 = (const float*)d_in[7];
  const float* Ws2 = (const float*)d_in[8];
  const float* Wn2 = (const float*)d_in[9];
  const float* b2 = (const float*)d_in[10];
  const float* Ws3 = (const float*)d_in[11];
  const float* Wn3 = (const float*)d_in[12];
  const float* b3 = (const float*)d_in[13];
  const float* Wp1 = (const float*)d_in[14];
  const float* bp1 = (const float*)d_in[15];
  const float* Wp2 = (const float*)d_in[16];
  const float* bp2 = (const float*)d_in[17];
  float* out = (float*)d_out;

  char* ws = (char*)d_ws;
  size_t off = 0;
  auto alloc = [&](size_t bytes) -> void* {
    void* p = ws + off;
    off += (bytes + 255) & ~(size_t)255;
    return p;
  };
  const size_t NODE_F32 = sizeof(float) * (size_t)N_NODES * D;  // 51.2 MB
  char* region0 = (char*)alloc(NODE_F32);   // bf16 xb | (spare) -> later bf16 Ab | Bb
  char* region1 = (char*)alloc(NODE_F32);   // bf16 hA | hB
  int* row_start = (int*)alloc(sizeof(int) * (N_NODES + 1));
  int* deg = (int*)alloc(sizeof(int) * N_NODES * 2);  // deg + cursor
  int* cursor = deg + N_NODES;
  int* esrc = (int*)alloc(sizeof(int) * N_EDGES);
  int* partial = (int*)alloc(sizeof(int) * 128);
  unsigned short* wt = (unsigned short*)alloc(sizeof(unsigned short) * 8 * D * D);
  (void)ws_size;

  unsigned short* xb = (unsigned short*)region0;
  unsigned short* hA = (unsigned short*)region1;
  unsigned short* hB = hA + (size_t)N_NODES * D;
  unsigned short* Ab = xb;                              // xb dead after layer-1 kernel
  unsigned short* Bb = xb + (size_t)N_NODES * D;        // second half of region0 (unused otherwise)

  // ---- conversions
  f32_to_bf16_vec<<<(N_NODES * D / 4 + 255) / 256, 256, 0, stream>>>(x, xb, N_NODES * D / 4);
  transpose_w<<<512, 256, 0, stream>>>(Ws1, Wn1, Ws2, Wn2, Ws3, Wn3, Wp1, Wp1 + D * D, wt);

  // ---- CSR build (pos edges; reused by all 3 layers)
  zero_i32<<<(2 * N_NODES + 255) / 256, 256, 0, stream>>>(deg, 2 * N_NODES);
  hist_kernel<<<(N_EDGES + 255) / 256, 256, 0, stream>>>(dst, deg, N_EDGES);
  scan_blocksum<<<SCAN_BLOCKS, 256, 0, stream>>>(deg, partial, N_NODES);
  scan_offsets<<<1, 128, 0, stream>>>(partial, row_start, SCAN_BLOCKS, N_NODES);
  scan_final<<<SCAN_BLOCKS, 256, 0, stream>>>(deg, partial, row_start, N_NODES);
  fill_kernel<<<(N_EDGES + 255) / 256, 256, 0, stream>>>(src, dst, row_start, cursor, esrc, N_EDGES);

  const int layerBlocks = (N_NODES + 63) / 64;
  const int edgeBlocks = (N_EDGES * 16) / 256;  // 16 lanes/edge-pair

  // ---- layer 1: h1 = x@Ws1 + mean(x)@Wn1 + b1  (mean via LDS)
  layer_fused<false><<<layerBlocks, 256, 0, stream>>>(
      xb, row_start, esrc, wt, wt + 16384, b1, nullptr, nullptr, nullptr, hA, nullptr, N_NODES);
  // ---- layer 2
  layer_fused<false><<<layerBlocks, 256, 0, stream>>>(
      hA, row_start, esrc, wt + 2 * 16384, wt + 3 * 16384, b2, nullptr, nullptr, nullptr, hB, nullptr, N_NODES);
  // ---- layer 3 + predictor: Ab = h3@Wp1_top + bp1, Bb = h3@Wp1_bot (h3 never leaves LDS)
  layer_fused<true><<<layerBlocks, 256, 0, stream>>>(
      hB, row_start, esrc, wt + 4 * 16384, wt + 5 * 16384, b3, wt + 6 * 16384, wt + 7 * 16384, bp1,
      Ab, Bb, N_NODES);
  // ---- edge scores (pos + neg fused)
  edge_score_fused<<<edgeBlocks, 256, 0, stream>>>(Ab, Bb, src, dst, nsrc, ndst, Wp2, bp2, out, N_EDGES);
}

// Round 14
// 479.427 us; speedup vs baseline: 1.3110x; 1.0438x over previous
//
#include <hip/hip_runtime.h>

#define N_NODES 100000
#define N_EDGES 640000
#define D 128
#define SCAN_TILE 1024
#define SCAN_BLOCKS ((N_NODES + SCAN_TILE - 1) / SCAN_TILE)  // 98

typedef __attribute__((ext_vector_type(8))) short bf16x8;   // 8 bf16 = 4 VGPRs
typedef __attribute__((ext_vector_type(4))) float f32x4;

__device__ __forceinline__ unsigned short f32_to_bf16(float f) {
  union { float f; unsigned int u; } v; v.f = f;
  unsigned int u = v.u;
  unsigned int r = (u + 0x7fffu + ((u >> 16) & 1u)) >> 16;  // RNE
  return (unsigned short)r;
}
__device__ __forceinline__ float bf16_lo(unsigned int u) { return __uint_as_float(u << 16); }
__device__ __forceinline__ float bf16_hi(unsigned int u) { return __uint_as_float(u & 0xffff0000u); }

__device__ __forceinline__ void acc8(float* a, uint4 r) {
  a[0] += bf16_lo(r.x); a[1] += bf16_hi(r.x);
  a[2] += bf16_lo(r.y); a[3] += bf16_hi(r.y);
  a[4] += bf16_lo(r.z); a[5] += bf16_hi(r.z);
  a[6] += bf16_lo(r.w); a[7] += bf16_hi(r.w);
}

// ---------------------------------------------------------------- utilities
__global__ void zero_i32(int* __restrict__ p, int n) {
  int i = blockIdx.x * blockDim.x + threadIdx.x;
  if (i < n) p[i] = 0;
}

__global__ void f32_to_bf16_vec(const float* __restrict__ in, unsigned short* __restrict__ out, int n4) {
  int i = blockIdx.x * blockDim.x + threadIdx.x;
  if (i < n4) {
    float4 v = ((const float4*)in)[i];
    ushort4 o;
    o.x = f32_to_bf16(v.x); o.y = f32_to_bf16(v.y);
    o.z = f32_to_bf16(v.z); o.w = f32_to_bf16(v.w);
    ((ushort4*)out)[i] = o;
  }
}

// 8 weight matrices [128x128] fp32 row-major [k][n] -> bf16 transposed Wt[n][k]
__global__ void transpose_w(const float* __restrict__ W0, const float* __restrict__ W1,
                            const float* __restrict__ W2, const float* __restrict__ W3,
                            const float* __restrict__ W4, const float* __restrict__ W5,
                            const float* __restrict__ W6, const float* __restrict__ W7,
                            unsigned short* __restrict__ wt) {
  int id = blockIdx.x * 256 + threadIdx.x;  // 512 blocks x 256 = 131072
  int mat = id >> 14;
  int rem = id & 16383;
  int n = rem >> 7, k = rem & 127;
  const float* Wm = mat < 4 ? (mat < 2 ? (mat == 0 ? W0 : W1) : (mat == 2 ? W2 : W3))
                            : (mat < 6 ? (mat == 4 ? W4 : W5) : (mat == 6 ? W6 : W7));
  wt[id] = f32_to_bf16(Wm[k * D + n]);
}

// ------------------------------------------------------------- CSR building (pos edges only)
__global__ void hist_kernel(const int* __restrict__ dst, int* __restrict__ deg, int E) {
  int i = blockIdx.x * blockDim.x + threadIdx.x;
  if (i < E) atomicAdd(&deg[dst[i]], 1);
}

__global__ void scan_blocksum(const int* __restrict__ deg, int* __restrict__ partial, int n) {
  __shared__ int lds[256];
  const int tid = threadIdx.x;
  const int base = blockIdx.x * SCAN_TILE + tid * 4;
  int s = 0;
#pragma unroll
  for (int j = 0; j < 4; ++j) {
    int i = base + j;
    if (i < n) s += deg[i];
  }
  lds[tid] = s;
  __syncthreads();
  for (int off = 128; off > 0; off >>= 1) {
    if (tid < off) lds[tid] += lds[tid + off];
    __syncthreads();
  }
  if (tid == 0) partial[blockIdx.x] = lds[0];
}

__global__ void scan_offsets(int* __restrict__ partial, int* __restrict__ row_start, int nb, int n) {
  __shared__ int lds[128];
  const int tid = threadIdx.x;
  int v = (tid < nb) ? partial[tid] : 0;
  lds[tid] = v;
  __syncthreads();
  for (int off = 1; off < 128; off <<= 1) {
    int t = (tid >= off) ? lds[tid - off] : 0;
    __syncthreads();
    lds[tid] += t;
    __syncthreads();
  }
  if (tid < nb) partial[tid] = (tid == 0) ? 0 : lds[tid - 1];
  if (tid == 0) row_start[n] = lds[nb - 1];
}

__global__ void scan_final(const int* __restrict__ deg, const int* __restrict__ partial,
                           int* __restrict__ row_start, int n) {
  __shared__ int lds[256];
  const int tid = threadIdx.x;
  const int base = blockIdx.x * SCAN_TILE + tid * 4;
  int d[4];
  int s = 0;
#pragma unroll
  for (int j = 0; j < 4; ++j) {
    int i = base + j;
    d[j] = (i < n) ? deg[i] : 0;
    s += d[j];
  }
  lds[tid] = s;
  __syncthreads();
  for (int off = 1; off < 256; off <<= 1) {
    int t = (tid >= off) ? lds[tid - off] : 0;
    __syncthreads();
    lds[tid] += t;
    __syncthreads();
  }
  int pre = partial[blockIdx.x] + lds[tid] - s;
#pragma unroll
  for (int j = 0; j < 4; ++j) {
    int i = base + j;
    if (i < n) {
      row_start[i] = pre;
      pre += d[j];
    }
  }
}

__global__ void fill_kernel(const int* __restrict__ src, const int* __restrict__ dst,
                            const int* __restrict__ row_start, int* __restrict__ cursor,
                            int* __restrict__ esrc, int E) {
  int i = blockIdx.x * blockDim.x + threadIdx.x;
  if (i < E) {
    int d = dst[i];
    int pos = atomicAdd(&cursor[d], 1);
    esrc[row_start[d] + pos] = src[i];
  }
}

// ----------------------------------------------------- fused SAGE layer
// Block = 64 nodes. Phase 1: gather mean(h[neigh]) -> LDS tile (never global).
// Phase 2: out = h@Ws + mean@Wn + b via MFMA, half-n weight panels in LDS.
// EPILOGUE: coalesced via LDS transpose. Per-lane 2-byte scattered stores
// caused 2x write amplification (WRITE_SIZE 50 MB for 25.6 MB output: partial
// 64B lines evicted then RMW-refetched). acc -> mt (b16 LDS scatter, cheap)
// -> barrier -> uint4 (16B) contiguous global stores covering the FULL
// 64x128 tile (1024 16B chunks = 4 iterations x 256 threads; round-13's 2-iter
// version only stored columns 0..63 -> correctness failure).
// PRED variant (layer 3): keep h3 in LDS, two more weight matrices produce
// A = h3@WtA + biasA and B = h3@WtB directly (h3 never hits HBM).
template <bool PRED>
__global__ __launch_bounds__(256) void layer_fused(
    const unsigned short* __restrict__ hin,
    const int* __restrict__ row_start, const int* __restrict__ esrc,
    const unsigned short* __restrict__ Wts, const unsigned short* __restrict__ Wtn,
    const float* __restrict__ bias,
    const unsigned short* __restrict__ WtA, const unsigned short* __restrict__ WtB,
    const float* __restrict__ biasA,
    unsigned short* __restrict__ out0, unsigned short* __restrict__ out1, int M) {
  __shared__ unsigned short wl[64][136];   // 17.4 KB half-n weight panel
  __shared__ unsigned short mt[64][136];   // 17.4 KB mean tile (reused: h3 tile, epilogue tile)
  const int tid = threadIdx.x;
  const int lane = tid & 63;
  const int wave = tid >> 6;
  const int m0 = blockIdx.x * 64;
  const int row = lane & 15;
  const int q = lane >> 4;
  const int mw = m0 + wave * 16;
  const int mload = min(mw + row, M - 1);

  // stage rows [half*64, half*64+64) of a transposed weight matrix into wl
  auto stage64 = [&](const unsigned short* W, int half) {
#pragma unroll
    for (int i = 0; i < 4; ++i) {
      int seg = i * 256 + tid;
      int r = seg >> 4, o = (seg & 15) * 8;
      *reinterpret_cast<bf16x8*>(&wl[r][o]) =
          *reinterpret_cast<const bf16x8*>(W + (size_t)(half * 64 + r) * D + o);
    }
  };
  // 16 MFMAs of one half-panel into acc[base..base+3]
  auto mfma_half = [&](bf16x8* a, f32x4* accp) {
#pragma unroll
    for (int s = 0; s < 4; ++s)
#pragma unroll
      for (int t = 0; t < 4; ++t) {
        bf16x8 b = *reinterpret_cast<const bf16x8*>(&wl[t * 16 + row][s * 32 + q * 8]);
        accp[t] = __builtin_amdgcn_mfma_f32_16x16x32_bf16(a[s], b, accp[t], 0, 0, 0);
      }
  };
  // coalesced epilogue: acc (+bias) -> mt -> contiguous uint4 global stores.
  // Preconditions: mt's previous readers are past a barrier (see call sites).
  auto epilogue = [&](f32x4* accp, const float* bvec, unsigned short* dst) {
#pragma unroll
    for (int t = 0; t < 8; ++t) {
      const int col = t * 16 + row;
      const float bv = bvec ? bvec[col] : 0.f;
#pragma unroll
      for (int r = 0; r < 4; ++r)
        mt[wave * 16 + q * 4 + r][col] = f32_to_bf16(accp[t][r] + bv);
    }
    __syncthreads();
    // full tile = 64 rows x 16 chunks of 16B = 1024 chunks, 4 per thread
#pragma unroll
    for (int i = 0; i < 4; ++i) {
      int idx = i * 256 + tid;
      int r2 = idx >> 4;
      int c8 = (idx & 15) * 8;
      int m = m0 + r2;
      if (m < M)
        *reinterpret_cast<uint4*>(dst + (size_t)m * D + c8) =
            *reinterpret_cast<const uint4*>(&mt[r2][c8]);
    }
  };

  // ---- A fragments of hin ----
  bf16x8 ah[4];
#pragma unroll
  for (int s = 0; s < 4; ++s)
    ah[s] = *reinterpret_cast<const bf16x8*>(hin + (size_t)mload * D + s * 32 + q * 8);

  // ---- stage Ws half 0 (overlaps with gather; gather doesn't touch wl) ----
  stage64(Wts, 0);

  // ---- phase 1: gather means into mt. group g (16 lanes) handles 4 nodes ----
  {
    const int g = tid >> 4;   // 0..15
    const int fl = tid & 15;  // feature lane, 16 B each
    for (int j = 0; j < 4; ++j) {
      const int node = m0 + g * 4 + j;
      float ac[8] = {0.f, 0.f, 0.f, 0.f, 0.f, 0.f, 0.f, 0.f};
      if (node < M) {
        const int s0 = row_start[node], s1 = row_start[node + 1];
        int e = s0;
        for (; e + 4 <= s1; e += 4) {
          int i0 = esrc[e], i1 = esrc[e + 1], i2 = esrc[e + 2], i3 = esrc[e + 3];
          uint4 r0 = *(const uint4*)(hin + (size_t)i0 * D + fl * 8);
          uint4 r1 = *(const uint4*)(hin + (size_t)i1 * D + fl * 8);
          uint4 r2 = *(const uint4*)(hin + (size_t)i2 * D + fl * 8);
          uint4 r3 = *(const uint4*)(hin + (size_t)i3 * D + fl * 8);
          acc8(ac, r0); acc8(ac, r1); acc8(ac, r2); acc8(ac, r3);
        }
        for (; e < s1; ++e) {
          uint4 r0 = *(const uint4*)(hin + (size_t)esrc[e] * D + fl * 8);
          acc8(ac, r0);
        }
        const float inv = 1.0f / (float)max(s1 - s0, 1);
#pragma unroll
        for (int k = 0; k < 8; ++k) ac[k] *= inv;
      }
      uint4 o;
      o.x = (unsigned)f32_to_bf16(ac[0]) | ((unsigned)f32_to_bf16(ac[1]) << 16);
      o.y = (unsigned)f32_to_bf16(ac[2]) | ((unsigned)f32_to_bf16(ac[3]) << 16);
      o.z = (unsigned)f32_to_bf16(ac[4]) | ((unsigned)f32_to_bf16(ac[5]) << 16);
      o.w = (unsigned)f32_to_bf16(ac[6]) | ((unsigned)f32_to_bf16(ac[7]) << 16);
      *reinterpret_cast<uint4*>(&mt[g * 4 + j][fl * 8]) = o;
    }
  }
  __syncthreads();  // wl = Ws[0:64) and mt = mean ready

  // ---- mean A-fragments from LDS ----
  const int lrow = wave * 16 + row;  // local row 0..63
  bf16x8 am[4];
#pragma unroll
  for (int s = 0; s < 4; ++s)
    am[s] = *reinterpret_cast<const bf16x8*>(&mt[lrow][s * 32 + q * 8]);

  f32x4 acc[8];
#pragma unroll
  for (int t = 0; t < 8; ++t) acc[t] = (f32x4){0.f, 0.f, 0.f, 0.f};

  mfma_half(ah, acc);                 // hin @ Ws, n 0..63
  __syncthreads(); stage64(Wts, 1); __syncthreads();
  mfma_half(ah, acc + 4);             // hin @ Ws, n 64..127
  __syncthreads(); stage64(Wtn, 0); __syncthreads();
  mfma_half(am, acc);                 // mean @ Wn, n 0..63
  __syncthreads(); stage64(Wtn, 1); __syncthreads();
  mfma_half(am, acc + 4);             // mean @ Wn, n 64..127
  // am loads precede the stage64(Wts,1) barrier in all waves -> mt overwrite safe.

  if (!PRED) {
    epilogue(acc, bias, out0);
    return;
  }

  // ================= PRED tail (layer 3) =================
  __syncthreads();  // all waves done with wl(Wtn half1) before restage
  // ---- h3 (bf16, bias applied) into mt; stage WtA half 0 ----
#pragma unroll
  for (int t = 0; t < 8; ++t) {
    const int col = t * 16 + row;
    const float bv = bias[col];
#pragma unroll
    for (int r = 0; r < 4; ++r)
      mt[wave * 16 + q * 4 + r][col] = f32_to_bf16(acc[t][r] + bv);
  }
  stage64(WtA, 0);
  __syncthreads();
  // ---- h3 A-fragments (each wave reads only rows it wrote) ----
  bf16x8 ap[4];
#pragma unroll
  for (int s = 0; s < 4; ++s)
    ap[s] = *reinterpret_cast<const bf16x8*>(&mt[lrow][s * 32 + q * 8]);

#pragma unroll
  for (int t = 0; t < 8; ++t) acc[t] = (f32x4){0.f, 0.f, 0.f, 0.f};
  mfma_half(ap, acc);                 // h3 @ WtA, n 0..63
  __syncthreads(); stage64(WtA, 1); __syncthreads();
  mfma_half(ap, acc + 4);             // h3 @ WtA, n 64..127
  // ap loads precede the stage64(WtA,1) barrier -> mt overwrite safe.
  epilogue(acc, biasA, out0);         // Ab coalesced
  __syncthreads(); stage64(WtB, 0); __syncthreads();
#pragma unroll
  for (int t = 0; t < 8; ++t) acc[t] = (f32x4){0.f, 0.f, 0.f, 0.f};
  mfma_half(ap, acc);                 // h3 @ WtB, n 0..63
  __syncthreads(); stage64(WtB, 1); __syncthreads();
  mfma_half(ap, acc + 4);             // h3 @ WtB, n 64..127
  // epilogue-A's mt reads precede the stage64(WtB,0) barrier -> overwrite safe.
  epilogue(acc, nullptr, out1);       // Bb coalesced
}

// ----------------------------------------------------- fused pos+neg edge MLP score
// group g scores pos edge g AND neg edge g: 4 independent row gathers in flight.
// score = relu(A[s]+B[d]).Wp2 + bp2  (bp1 folded into A)
__global__ void edge_score_fused(const unsigned short* __restrict__ A, const unsigned short* __restrict__ B,
                                 const int* __restrict__ ps, const int* __restrict__ pd,
                                 const int* __restrict__ ns, const int* __restrict__ nd,
                                 const float* __restrict__ Wp2, const float* __restrict__ bp2,
                                 float* __restrict__ out, int E) {
  const int t = blockIdx.x * blockDim.x + threadIdx.x;
  const int e = t >> 4;                 // 16 lanes per edge pair
  const int fl = threadIdx.x & 15;
  if (e >= E) return;
  const int si = ps[e], di = pd[e];
  const int nsi = ns[e], ndi = nd[e];
  uint4 ra = *(const uint4*)(A + (size_t)si * D + fl * 8);
  uint4 rb = *(const uint4*)(B + (size_t)di * D + fl * 8);
  uint4 rna = *(const uint4*)(A + (size_t)nsi * D + fl * 8);
  uint4 rnb = *(const uint4*)(B + (size_t)ndi * D + fl * 8);
  float4 w0 = *(const float4*)(Wp2 + fl * 8);
  float4 w1 = *(const float4*)(Wp2 + fl * 8 + 4);

  float pp =
      fmaxf(bf16_lo(ra.x) + bf16_lo(rb.x), 0.f) * w0.x +
      fmaxf(bf16_hi(ra.x) + bf16_hi(rb.x), 0.f) * w0.y +
      fmaxf(bf16_lo(ra.y) + bf16_lo(rb.y), 0.f) * w0.z +
      fmaxf(bf16_hi(ra.y) + bf16_hi(rb.y), 0.f) * w0.w +
      fmaxf(bf16_lo(ra.z) + bf16_lo(rb.z), 0.f) * w1.x +
      fmaxf(bf16_hi(ra.z) + bf16_hi(rb.z), 0.f) * w1.y +
      fmaxf(bf16_lo(ra.w) + bf16_lo(rb.w), 0.f) * w1.z +
      fmaxf(bf16_hi(ra.w) + bf16_hi(rb.w), 0.f) * w1.w;
  float pn =
      fmaxf(bf16_lo(rna.x) + bf16_lo(rnb.x), 0.f) * w0.x +
      fmaxf(bf16_hi(rna.x) + bf16_hi(rnb.x), 0.f) * w0.y +
      fmaxf(bf16_lo(rna.y) + bf16_lo(rnb.y), 0.f) * w0.z +
      fmaxf(bf16_hi(rna.y) + bf16_hi(rnb.y), 0.f) * w0.w +
      fmaxf(bf16_lo(rna.z) + bf16_lo(rnb.z), 0.f) * w1.x +
      fmaxf(bf16_hi(rna.z) + bf16_hi(rnb.z), 0.f) * w1.y +
      fmaxf(bf16_lo(rna.w) + bf16_lo(rnb.w), 0.f) * w1.z +
      fmaxf(bf16_hi(rna.w) + bf16_hi(rnb.w), 0.f) * w1.w;

  pp += __shfl_xor(pp, 1);  pn += __shfl_xor(pn, 1);
  pp += __shfl_xor(pp, 2);  pn += __shfl_xor(pn, 2);
  pp += __shfl_xor(pp, 4);  pn += __shfl_xor(pn, 4);
  pp += __shfl_xor(pp, 8);  pn += __shfl_xor(pn, 8);
  if (fl == 0) {
    float b = bp2[0];
    out[e] = pp + b;
    out[E + e] = pn + b;
  }
}

// ---------------------------------------------------------------- launcher
extern "C" void kernel_launch(void* const* d_in, const int* in_sizes, int n_in,
                              void* d_out, int out_size, void* d_ws, size_t ws_size,
                              hipStream_t stream) {
  const float* x = (const float*)d_in[0];
  const int* src = (const int*)d_in[1];
  const int* dst = (const int*)d_in[2];
  const int* nsrc = (const int*)d_in[3];
  const int* ndst = (const int*)d_in[4];
  const float* Ws1 = (const float*)d_in[5];
  const float* Wn1 = (const float*)d_in[6];
  const float* b1 = (const float*)d_in[7];
  const float* Ws2 = (const float*)d_in[8];
  const float* Wn2 = (const float*)d_in[9];
  const float* b2 = (const float*)d_in[10];
  const float* Ws3 = (const float*)d_in[11];
  const float* Wn3 = (const float*)d_in[12];
  const float* b3 = (const float*)d_in[13];
  const float* Wp1 = (const float*)d_in[14];
  const float* bp1 = (const float*)d_in[15];
  const float* Wp2 = (const float*)d_in[16];
  const float* bp2 = (const float*)d_in[17];
  float* out = (float*)d_out;

  char* ws = (char*)d_ws;
  size_t off = 0;
  auto alloc = [&](size_t bytes) -> void* {
    void* p = ws + off;
    off += (bytes + 255) & ~(size_t)255;
    return p;
  };
  const size_t NODE_F32 = sizeof(float) * (size_t)N_NODES * D;  // 51.2 MB
  char* region0 = (char*)alloc(NODE_F32);   // bf16 xb | (spare) -> later bf16 Ab | Bb
  char* region1 = (char*)alloc(NODE_F32);   // bf16 hA | hB
  int* row_start = (int*)alloc(sizeof(int) * (N_NODES + 1));
  int* deg = (int*)alloc(sizeof(int) * N_NODES * 2);  // deg + cursor
  int* cursor = deg + N_NODES;
  int* esrc = (int*)alloc(sizeof(int) * N_EDGES);
  int* partial = (int*)alloc(sizeof(int) * 128);
  unsigned short* wt = (unsigned short*)alloc(sizeof(unsigned short) * 8 * D * D);
  (void)ws_size;

  unsigned short* xb = (unsigned short*)region0;
  unsigned short* hA = (unsigned short*)region1;
  unsigned short* hB = hA + (size_t)N_NODES * D;
  unsigned short* Ab = xb;                              // xb dead after layer-1 kernel
  unsigned short* Bb = xb + (size_t)N_NODES * D;        // second half of region0 (unused otherwise)

  // ---- conversions
  f32_to_bf16_vec<<<(N_NODES * D / 4 + 255) / 256, 256, 0, stream>>>(x, xb, N_NODES * D / 4);
  transpose_w<<<512, 256, 0, stream>>>(Ws1, Wn1, Ws2, Wn2, Ws3, Wn3, Wp1, Wp1 + D * D, wt);

  // ---- CSR build (pos edges; reused by all 3 layers)
  zero_i32<<<(2 * N_NODES + 255) / 256, 256, 0, stream>>>(deg, 2 * N_NODES);
  hist_kernel<<<(N_EDGES + 255) / 256, 256, 0, stream>>>(dst, deg, N_EDGES);
  scan_blocksum<<<SCAN_BLOCKS, 256, 0, stream>>>(deg, partial, N_NODES);
  scan_offsets<<<1, 128, 0, stream>>>(partial, row_start, SCAN_BLOCKS, N_NODES);
  scan_final<<<SCAN_BLOCKS, 256, 0, stream>>>(deg, partial, row_start, N_NODES);
  fill_kernel<<<(N_EDGES + 255) / 256, 256, 0, stream>>>(src, dst, row_start, cursor, esrc, N_EDGES);

  const int layerBlocks = (N_NODES + 63) / 64;
  const int edgeBlocks = (N_EDGES * 16) / 256;  // 16 lanes/edge-pair

  // ---- layer 1: h1 = x@Ws1 + mean(x)@Wn1 + b1  (mean via LDS)
  layer_fused<false><<<layerBlocks, 256, 0, stream>>>(
      xb, row_start, esrc, wt, wt + 16384, b1, nullptr, nullptr, nullptr, hA, nullptr, N_NODES);
  // ---- layer 2
  layer_fused<false><<<layerBlocks, 256, 0, stream>>>(
      hA, row_start, esrc, wt + 2 * 16384, wt + 3 * 16384, b2, nullptr, nullptr, nullptr, hB, nullptr, N_NODES);
  // ---- layer 3 + predictor: Ab = h3@Wp1_top + bp1, Bb = h3@Wp1_bot (h3 never leaves LDS)
  layer_fused<true><<<layerBlocks, 256, 0, stream>>>(
      hB, row_start, esrc, wt + 4 * 16384, wt + 5 * 16384, b3, wt + 6 * 16384, wt + 7 * 16384, bp1,
      Ab, Bb, N_NODES);
  // ---- edge scores (pos + neg fused)
  edge_score_fused<<<edgeBlocks, 256, 0, stream>>>(Ab, Bb, src, dst, nsrc, ndst, Wp2, bp2, out, N_EDGES);
}